// Round 1
// baseline (2195.931 us; speedup 1.0000x reference)
//
#include <hip/hip_runtime.h>
#include <math.h>

#define NN 100000
#define NE 1600000
#define CC 128
#define C3 384

__device__ __forceinline__ float sigmoidf_(float x) { return 1.0f / (1.0f + __expf(-x)); }
// tanh via exp; saturates correctly at +/-inf
__device__ __forceinline__ float tanhf_(float x) { return 2.0f / (1.0f + __expf(-2.0f * x)) - 1.0f; }

// ---- edge dtype detection: int64 => every odd int32 word is a zero high-word ----
__global__ void k_detect(const int* __restrict__ edges, int* __restrict__ flag) {
    if (threadIdx.x == 0) {
        int allz = 1;
        for (int i = 0; i < 32; i++)
            if (edges[2 * i + 1] != 0) allz = 0;
        *flag = allz;  // 1 => int64 layout
    }
}

__device__ __forceinline__ int edge_val(const void* edges, int f, long long idx) {
    return f ? (int)((const long long*)edges)[idx] : ((const int*)edges)[idx];
}

__global__ void k_count(const void* __restrict__ edges, const int* __restrict__ flag,
                        int* __restrict__ counts) {
    int e = blockIdx.x * blockDim.x + threadIdx.x;
    if (e < NE) {
        int f = *flag;
        int d = edge_val(edges, f, (long long)NE + e);
        atomicAdd(&counts[d], 1);
    }
}

// single-block exclusive scan over counts -> rowptr; also inv_denom
__global__ void k_scan(const int* __restrict__ counts, int* __restrict__ rowptr,
                       float* __restrict__ inv_denom) {
    __shared__ int lds[1024];
    int t = threadIdx.x;
    const int CH = 98;  // 1024*98 >= 100000
    int lo = t * CH;
    int hi = lo + CH; if (hi > NN) hi = NN;
    int s = 0;
    for (int i = lo; i < hi; i++) s += counts[i];
    lds[t] = s;
    __syncthreads();
    for (int off = 1; off < 1024; off <<= 1) {
        int v = (t >= off) ? lds[t - off] : 0;
        __syncthreads();
        lds[t] += v;
        __syncthreads();
    }
    int base = (t == 0) ? 0 : lds[t - 1];
    for (int i = lo; i < hi; i++) {
        rowptr[i] = base;
        int c = counts[i];
        inv_denom[i] = 1.0f / (float)((c > 1) ? c : 1);
        base += c;
    }
    if (t == 0) rowptr[NN] = NE;
}

__global__ void k_bucket(const void* __restrict__ edges, const int* __restrict__ flag,
                         const int* __restrict__ rowptr, int* __restrict__ cursor,
                         int* __restrict__ csr_src) {
    int e = blockIdx.x * blockDim.x + threadIdx.x;
    if (e < NE) {
        int f = *flag;
        int s = edge_val(edges, f, e);
        int d = edge_val(edges, f, (long long)NE + e);
        int pos = atomicAdd(&cursor[d], 1);
        csr_src[rowptr[d] + pos] = s;
    }
}

// Wct[i][k][j] = sum_c weight[i][k][c] * w_ih[j][c]   (layout [i][k*384+j])
// Whht[k][j]  = w_hh[j][k]
__global__ void k_prep_w(const float* __restrict__ weight, const float* __restrict__ w_ih,
                         const float* __restrict__ w_hh,
                         float* __restrict__ Wct, float* __restrict__ Whht) {
    int gid = blockIdx.x * blockDim.x + threadIdx.x;
    if (gid < 3 * CC * C3) {
        int i = gid / (CC * C3);
        int rem = gid % (CC * C3);
        int k = rem / C3;
        int j = rem % C3;
        const float* Wr = weight + i * CC * CC + k * CC;
        const float* ir = w_ih + j * CC;
        float s = 0.f;
#pragma unroll 4
        for (int c = 0; c < CC; c++) s += Wr[c] * ir[c];
        Wct[gid] = s;
    } else {
        int g2 = gid - 3 * CC * C3;
        if (g2 < CC * C3) {
            int k = g2 / C3;
            int j = g2 % C3;
            Whht[g2] = w_hh[j * CC + k];
        }
    }
}

// one wave per node: a_hat[n] = (sum over in-edges of h[src]) * inv_denom[n]
__global__ void k_agg(const float* __restrict__ h, const int* __restrict__ rowptr,
                      const int* __restrict__ csr_src, const float* __restrict__ inv_denom,
                      float* __restrict__ a_hat) {
    int wid = (blockIdx.x * blockDim.x + threadIdx.x) >> 6;
    int lane = threadIdx.x & 63;
    if (wid >= NN) return;
    int lo = rowptr[wid], hi = rowptr[wid + 1];
    float ax = 0.f, ay = 0.f;
    for (int e = lo; e < hi; e++) {
        int s = csr_src[e];
        float2 v = ((const float2*)(h + (long long)s * CC))[lane];
        ax += v.x; ay += v.y;
    }
    float inv = inv_denom[wid];
    float2 r; r.x = ax * inv; r.y = ay * inv;
    ((float2*)(a_hat + (long long)wid * CC))[lane] = r;
}

// fused GEMM + GRU: 16 nodes per block, 256 threads.
// thread t: feature j = t&127, node-group half = t>>7 (8 nodes each).
// computes 6 dot products (i_r,i_z,i_n,h_r,h_z,h_n) per (node, feature), then gates.
__global__ __launch_bounds__(256) void k_gru(const float* __restrict__ a_hat,
                                             const float* __restrict__ h,
                                             const float* __restrict__ Wct,
                                             const float* __restrict__ Whht,
                                             const float* __restrict__ b_ih,
                                             const float* __restrict__ b_hh,
                                             float* __restrict__ h_out) {
    __shared__ float sA[16 * CC];
    __shared__ float sH[16 * CC];
    int t = threadIdx.x;
    long long nb = (long long)blockIdx.x * 16;

    const float4* gA = (const float4*)(a_hat + nb * CC);
    const float4* gH = (const float4*)(h + nb * CC);
    float4* lA = (float4*)sA;
    float4* lH = (float4*)sH;
    lA[t] = gA[t]; lA[t + 256] = gA[t + 256];
    lH[t] = gH[t]; lH[t + 256] = gH[t + 256];
    __syncthreads();

    int j = t & 127;
    int half = t >> 7;

    float ir[8], iz[8], in_[8], hr[8], hz[8], hn[8];
    float bir = b_ih[j], biz = b_ih[CC + j], bin = b_ih[2 * CC + j];
    float bhr = b_hh[j], bhz = b_hh[CC + j], bhn = b_hh[2 * CC + j];
#pragma unroll
    for (int n = 0; n < 8; n++) {
        ir[n] = bir; iz[n] = biz; in_[n] = bin;
        hr[n] = bhr; hz[n] = bhz; hn[n] = bhn;
    }

    const float4* A4 = (const float4*)(sA + half * 8 * CC);
    const float4* H4 = (const float4*)(sH + half * 8 * CC);

    for (int k = 0; k < CC; k += 4) {
        float w_ir[4], w_iz[4], w_in[4], w_hr[4], w_hz[4], w_hn[4];
#pragma unroll
        for (int q = 0; q < 4; q++) {
            const float* wc = Wct + (k + q) * C3;
            const float* wh = Whht + (k + q) * C3;
            w_ir[q] = wc[j];          w_iz[q] = wc[CC + j];  w_in[q] = wc[2 * CC + j];
            w_hr[q] = wh[j];          w_hz[q] = wh[CC + j];  w_hn[q] = wh[2 * CC + j];
        }
        int kv = k >> 2;
#pragma unroll
        for (int n = 0; n < 8; n++) {
            float4 av = A4[n * 32 + kv];
            float4 hv = H4[n * 32 + kv];
            ir[n] += av.x * w_ir[0] + av.y * w_ir[1] + av.z * w_ir[2] + av.w * w_ir[3];
            iz[n] += av.x * w_iz[0] + av.y * w_iz[1] + av.z * w_iz[2] + av.w * w_iz[3];
            in_[n] += av.x * w_in[0] + av.y * w_in[1] + av.z * w_in[2] + av.w * w_in[3];
            hr[n] += hv.x * w_hr[0] + hv.y * w_hr[1] + hv.z * w_hr[2] + hv.w * w_hr[3];
            hz[n] += hv.x * w_hz[0] + hv.y * w_hz[1] + hv.z * w_hz[2] + hv.w * w_hz[3];
            hn[n] += hv.x * w_hn[0] + hv.y * w_hn[1] + hv.z * w_hn[2] + hv.w * w_hn[3];
        }
    }

#pragma unroll
    for (int n = 0; n < 8; n++) {
        int node = half * 8 + n;
        float r = sigmoidf_(ir[n] + hr[n]);
        float z = sigmoidf_(iz[n] + hz[n]);
        float nn2 = tanhf_(in_[n] + r * hn[n]);
        float hp = sH[node * CC + j];
        h_out[(nb + node) * CC + j] = (1.f - z) * nn2 + z * hp;
    }
}

// out[n] = tanh(mean_c h[n][c]) — one wave per node
__global__ void k_out(const float* __restrict__ h, float* __restrict__ out) {
    int wid = (blockIdx.x * blockDim.x + threadIdx.x) >> 6;
    int lane = threadIdx.x & 63;
    if (wid >= NN) return;
    float2 v = ((const float2*)(h + (long long)wid * CC))[lane];
    float s = v.x + v.y;
    for (int off = 32; off; off >>= 1) s += __shfl_down(s, off);
    if (lane == 0) out[wid] = tanhf_(s * (1.0f / 128.0f));
}

extern "C" void kernel_launch(void* const* d_in, const int* in_sizes, int n_in,
                              void* d_out, int out_size, void* d_ws, size_t ws_size,
                              hipStream_t stream) {
    const float* x = (const float*)d_in[0];
    const void* edges = d_in[1];
    const float* weight = (const float*)d_in[2];
    const float* w_ih = (const float*)d_in[3];
    const float* w_hh = (const float*)d_in[4];
    const float* b_ih = (const float*)d_in[5];
    const float* b_hh = (const float*)d_in[6];
    float* out = (float*)d_out;

    char* ws = (char*)d_ws;
    size_t off = 0;
    auto alloc = [&](size_t bytes) -> char* {
        char* p = ws + off;
        off += (bytes + 255) & ~(size_t)255;
        return p;
    };
    int* flag = (int*)alloc(4);
    int* counts = (int*)alloc((size_t)NN * 4);
    int* cursor = (int*)alloc((size_t)NN * 4);
    int* rowptr = (int*)alloc((size_t)(NN + 1) * 4);
    int* csr_src = (int*)alloc((size_t)NE * 4);
    float* inv_den = (float*)alloc((size_t)NN * 4);
    float* Wct = (float*)alloc((size_t)3 * CC * C3 * 4);
    float* Whht = (float*)alloc((size_t)CC * C3 * 4);
    float* a_hat = (float*)alloc((size_t)NN * CC * 4);
    float* h0 = (float*)alloc((size_t)NN * CC * 4);
    float* h1 = (float*)alloc((size_t)NN * CC * 4);

    hipMemsetAsync(counts, 0, (size_t)NN * 4, stream);
    hipMemsetAsync(cursor, 0, (size_t)NN * 4, stream);

    k_detect<<<1, 64, 0, stream>>>((const int*)edges, flag);
    k_count<<<(NE + 255) / 256, 256, 0, stream>>>(edges, flag, counts);
    k_scan<<<1, 1024, 0, stream>>>(counts, rowptr, inv_den);
    k_bucket<<<(NE + 255) / 256, 256, 0, stream>>>(edges, flag, rowptr, cursor, csr_src);
    k_prep_w<<<(3 * CC * C3 + CC * C3 + 255) / 256, 256, 0, stream>>>(weight, w_ih, w_hh, Wct, Whht);

    const float* hc = x;
    float* bufs[2] = {h0, h1};
    for (int i = 0; i < 3; i++) {
        k_agg<<<25000, 256, 0, stream>>>(hc, rowptr, csr_src, inv_den, a_hat);
        float* hn = bufs[i & 1];
        k_gru<<<6250, 256, 0, stream>>>(a_hat, hc, Wct + (size_t)i * CC * C3, Whht, b_ih, b_hh, hn);
        hc = hn;
    }
    k_out<<<25000, 256, 0, stream>>>(hc, out);
}

// Round 2
// 1884.321 us; speedup vs baseline: 1.1654x; 1.1654x over previous
//
#include <hip/hip_runtime.h>
#include <math.h>

#define NN 100000
#define NE 1600000
#define CC 128
#define C3 384

typedef __attribute__((ext_vector_type(4))) float f4;
typedef __attribute__((ext_vector_type(8))) short s8;

__device__ __forceinline__ float sigmoidf_(float x) { return 1.0f / (1.0f + __expf(-x)); }
__device__ __forceinline__ float tanhf_(float x) { return 2.0f / (1.0f + __expf(-2.0f * x)) - 1.0f; }

__device__ __forceinline__ short f2bf(float x) {
    unsigned u = __float_as_uint(x);
    unsigned r = (u + 0x7fffu + ((u >> 16) & 1u)) >> 16;
    return (short)r;
}
__device__ __forceinline__ float bf2f(short s) {
    return __uint_as_float(((unsigned)(unsigned short)s) << 16);
}

// ---- edge dtype detection: int64 => every odd int32 word is a zero high-word ----
__global__ void k_detect(const int* __restrict__ edges, int* __restrict__ flag) {
    if (threadIdx.x == 0) {
        int allz = 1;
        for (int i = 0; i < 32; i++)
            if (edges[2 * i + 1] != 0) allz = 0;
        *flag = allz;  // 1 => int64 layout
    }
}

__device__ __forceinline__ int edge_val(const void* edges, int f, long long idx) {
    return f ? (int)((const long long*)edges)[idx] : ((const int*)edges)[idx];
}

__global__ void k_count(const void* __restrict__ edges, const int* __restrict__ flag,
                        int* __restrict__ counts) {
    int e = blockIdx.x * blockDim.x + threadIdx.x;
    if (e < NE) {
        int f = *flag;
        int d = edge_val(edges, f, (long long)NE + e);
        atomicAdd(&counts[d], 1);
    }
}

__global__ void k_scan(const int* __restrict__ counts, int* __restrict__ rowptr,
                       float* __restrict__ inv_denom) {
    __shared__ int lds[1024];
    int t = threadIdx.x;
    const int CH = 98;
    int lo = t * CH;
    int hi = lo + CH; if (hi > NN) hi = NN;
    int s = 0;
    for (int i = lo; i < hi; i++) s += counts[i];
    lds[t] = s;
    __syncthreads();
    for (int off = 1; off < 1024; off <<= 1) {
        int v = (t >= off) ? lds[t - off] : 0;
        __syncthreads();
        lds[t] += v;
        __syncthreads();
    }
    int base = (t == 0) ? 0 : lds[t - 1];
    for (int i = lo; i < hi; i++) {
        rowptr[i] = base;
        int c = counts[i];
        inv_denom[i] = 1.0f / (float)((c > 1) ? c : 1);
        base += c;
    }
    if (t == 0) rowptr[NN] = NE;
}

__global__ void k_bucket(const void* __restrict__ edges, const int* __restrict__ flag,
                         const int* __restrict__ rowptr, int* __restrict__ cursor,
                         int* __restrict__ csr_src) {
    int e = blockIdx.x * blockDim.x + threadIdx.x;
    if (e < NE) {
        int f = *flag;
        int s = edge_val(edges, f, e);
        int d = edge_val(edges, f, (long long)NE + e);
        int pos = atomicAdd(&cursor[d], 1);
        csr_src[rowptr[d] + pos] = s;
    }
}

// ---- weight prep: build per-layer MFMA B matrices (split bf16 hi/lo) ----
// B1[i][j][k]: j in [0,256) = r|z output rows; k<128 from Wc (=weight[i]@w_ih^T row j),
//              k>=128 from w_hh[j][k-128].   [256 x 256]
// B2[i][j][k]: j in [0,128): Wc n-block rows (w_ih rows 256..383);
//              j in [128,256): w_hh rows 256..383.   [256 x 128]
// bvec[512]: [b_ih[0:256]+b_hh[0:256], b_ih[256:384], b_hh[256:384]]
__global__ void k_prep(const float* __restrict__ weight, const float* __restrict__ w_ih,
                       const float* __restrict__ w_hh, const float* __restrict__ b_ih,
                       const float* __restrict__ b_hh,
                       short* __restrict__ B1hi, short* __restrict__ B1lo,
                       short* __restrict__ B2hi, short* __restrict__ B2lo,
                       float* __restrict__ bvec) {
    const int P1 = 3 * C3 * CC;  // Wc dot products
    int gid = blockIdx.x * blockDim.x + threadIdx.x;
    if (gid < P1) {
        int i = gid / (C3 * CC);
        int rem = gid % (C3 * CC);
        int j = rem / CC;
        int k = rem % CC;
        const float* Wr = weight + i * CC * CC + k * CC;
        const float* ir = w_ih + j * CC;
        float v = 0.f;
#pragma unroll 4
        for (int c = 0; c < CC; c++) v += Wr[c] * ir[c];
        short hi = f2bf(v);
        short lo = f2bf(v - bf2f(hi));
        if (j < 256) {
            int idx = i * 65536 + j * 256 + k;
            B1hi[idx] = hi; B1lo[idx] = lo;
        } else {
            int idx = i * 32768 + (j - 256) * 128 + k;
            B2hi[idx] = hi; B2lo[idx] = lo;
        }
    } else if (gid < 2 * P1) {
        int g = gid - P1;
        int i = g / (C3 * CC);
        int rem = g % (C3 * CC);
        int j = rem / CC;
        int k = rem % CC;
        float v = w_hh[j * CC + k];
        short hi = f2bf(v);
        short lo = f2bf(v - bf2f(hi));
        if (j < 256) {
            int idx = i * 65536 + j * 256 + 128 + k;
            B1hi[idx] = hi; B1lo[idx] = lo;
        } else {
            int idx = i * 32768 + (j - 256 + 128) * 128 + k;
            B2hi[idx] = hi; B2lo[idx] = lo;
        }
    } else if (gid < 2 * P1 + 512) {
        int j = gid - 2 * P1;
        float v;
        if (j < 256) v = b_ih[j] + b_hh[j];
        else if (j < 384) v = b_ih[j];          // i_n bias: b_ih[256..383]
        else v = b_hh[j - 128];                 // h_n bias: b_hh[256..383]
        bvec[j] = v;
    }
}

// ---- aggregation: one wave per node ----
__global__ void k_agg(const float* __restrict__ h, const int* __restrict__ rowptr,
                      const int* __restrict__ csr_src, const float* __restrict__ inv_denom,
                      float* __restrict__ a_hat) {
    int wid = (blockIdx.x * blockDim.x + threadIdx.x) >> 6;
    int lane = threadIdx.x & 63;
    if (wid >= NN) return;
    int lo = rowptr[wid], hi = rowptr[wid + 1];
    float ax = 0.f, ay = 0.f;
    for (int e = lo; e < hi; e++) {
        int s = csr_src[e];
        float2 v = ((const float2*)(h + (long long)s * CC))[lane];
        ax += v.x; ay += v.y;
    }
    float inv = inv_denom[wid];
    float2 r; r.x = ax * inv; r.y = ay * inv;
    ((float2*)(a_hat + (long long)wid * CC))[lane] = r;
}

// ---- fused split-bf16 MFMA GEMM + GRU ----
// Block: 256 threads (4 waves), 16 nodes.
// A_cat[node][k]: k<128 = a_hat, k>=128 = h. Split to bf16 hi/lo in LDS (row pad +8).
// 32 output n-tiles of 16: nt<16 -> G1 (s_r|s_z, K=256, B1); nt>=16 -> G2 (i_n|h_n, K=128, B2).
// Each MFMA: D=A*B^T, A[m=lane&15][k=(lane>>4)*8+j], B[n=lane&15][k=...],
// D col=lane&15, row=(lane>>4)*4+reg  (m89/m74-verified gfx950 mappings).
#define ASTR 264   // 256 + 8 pad (bf16 elems)
#define OSTR 516   // 512 + 4 pad (floats)
__global__ __launch_bounds__(256) void k_gru_mfma(
    const float* __restrict__ a_hat, const float* __restrict__ h,
    const short* __restrict__ B1hi, const short* __restrict__ B1lo,
    const short* __restrict__ B2hi, const short* __restrict__ B2lo,
    const float* __restrict__ bvec, float* __restrict__ h_out) {
    __shared__ short Ahi[16 * ASTR];
    __shared__ short Alo[16 * ASTR];
    __shared__ float sOut[16 * OSTR];
    int t = threadIdx.x;
    long long nb = (long long)blockIdx.x * 16;

    // stage + split A_cat: 16 nodes x 256 floats = 1024 float4, 4 per thread
#pragma unroll
    for (int i = 0; i < 4; i++) {
        int f = t + 256 * i;
        int node = f >> 6;
        int k = (f & 63) * 4;
        const float* srcp = (k < 128) ? (a_hat + (nb + node) * CC + k)
                                      : (h + (nb + node) * CC + (k - 128));
        float4 v = *(const float4*)srcp;
        short h0 = f2bf(v.x), h1 = f2bf(v.y), h2 = f2bf(v.z), h3 = f2bf(v.w);
        short l0 = f2bf(v.x - bf2f(h0)), l1 = f2bf(v.y - bf2f(h1));
        short l2 = f2bf(v.z - bf2f(h2)), l3 = f2bf(v.w - bf2f(h3));
        short4 sh = make_short4(h0, h1, h2, h3);
        short4 sl = make_short4(l0, l1, l2, l3);
        *(short4*)&Ahi[node * ASTR + k] = sh;
        *(short4*)&Alo[node * ASTR + k] = sl;
    }
    __syncthreads();

    int wv = t >> 6;
    int lane = t & 63;
    int lm = lane & 15;
    int lq = lane >> 4;

#pragma unroll 1
    for (int tt = 0; tt < 8; tt++) {
        int nt = wv * 8 + tt;  // 0..31
        int outbase, kbase, ksteps, bstride;
        const short *Bh, *Bl;
        int brow;
        if (nt < 16) {
            outbase = nt * 16; kbase = 0; ksteps = 8; bstride = 256;
            Bh = B1hi; Bl = B1lo; brow = nt * 16;
        } else {
            int j2 = (nt - 16) * 16;
            outbase = 256 + j2; ksteps = 4; bstride = 128;
            Bh = B2hi; Bl = B2lo; brow = j2;
            kbase = (j2 < 128) ? 0 : 128;
        }
        float bv = bvec[outbase + lm];
        f4 acc = {bv, bv, bv, bv};
        const short* bhp = Bh + (brow + lm) * bstride + lq * 8;
        const short* blp = Bl + (brow + lm) * bstride + lq * 8;
        const short* ahp = &Ahi[lm * ASTR + kbase + lq * 8];
        const short* alp = &Alo[lm * ASTR + kbase + lq * 8];
        for (int ks = 0; ks < ksteps; ks++) {
            s8 af_hi = *(const s8*)(ahp + ks * 32);
            s8 af_lo = *(const s8*)(alp + ks * 32);
            s8 bf_hi = *(const s8*)(bhp + ks * 32);
            s8 bf_lo = *(const s8*)(blp + ks * 32);
            acc = __builtin_amdgcn_mfma_f32_16x16x32_bf16(af_hi, bf_hi, acc, 0, 0, 0);
            acc = __builtin_amdgcn_mfma_f32_16x16x32_bf16(af_lo, bf_hi, acc, 0, 0, 0);
            acc = __builtin_amdgcn_mfma_f32_16x16x32_bf16(af_hi, bf_lo, acc, 0, 0, 0);
        }
#pragma unroll
        for (int r = 0; r < 4; r++)
            sOut[(lq * 4 + r) * OSTR + outbase + lm] = acc[r];
    }
    __syncthreads();

    // epilogue: 16 nodes x 128 features = 2048 items
#pragma unroll
    for (int it = 0; it < 8; it++) {
        int item = t + 256 * it;
        int node = item >> 7;
        int j = item & 127;
        float s_r = sOut[node * OSTR + j];
        float s_z = sOut[node * OSTR + 128 + j];
        float i_n = sOut[node * OSTR + 256 + j];
        float h_n = sOut[node * OSTR + 384 + j];
        float hp = bf2f(Ahi[node * ASTR + 128 + j]) + bf2f(Alo[node * ASTR + 128 + j]);
        float r = sigmoidf_(s_r);
        float z = sigmoidf_(s_z);
        float nv = tanhf_(i_n + r * h_n);
        h_out[(nb + node) * CC + j] = (1.f - z) * nv + z * hp;
    }
}

// ---- out[n] = tanh(mean_c h[n][c]) ----
__global__ void k_out(const float* __restrict__ h, float* __restrict__ out) {
    int wid = (blockIdx.x * blockDim.x + threadIdx.x) >> 6;
    int lane = threadIdx.x & 63;
    if (wid >= NN) return;
    float2 v = ((const float2*)(h + (long long)wid * CC))[lane];
    float s = v.x + v.y;
    for (int off = 32; off; off >>= 1) s += __shfl_down(s, off);
    if (lane == 0) out[wid] = tanhf_(s * (1.0f / 128.0f));
}

extern "C" void kernel_launch(void* const* d_in, const int* in_sizes, int n_in,
                              void* d_out, int out_size, void* d_ws, size_t ws_size,
                              hipStream_t stream) {
    const float* x = (const float*)d_in[0];
    const void* edges = d_in[1];
    const float* weight = (const float*)d_in[2];
    const float* w_ih = (const float*)d_in[3];
    const float* w_hh = (const float*)d_in[4];
    const float* b_ih = (const float*)d_in[5];
    const float* b_hh = (const float*)d_in[6];
    float* out = (float*)d_out;

    char* ws = (char*)d_ws;
    size_t off = 0;
    auto alloc = [&](size_t bytes) -> char* {
        char* p = ws + off;
        off += (bytes + 255) & ~(size_t)255;
        return p;
    };
    int* flag = (int*)alloc(4);
    int* counts = (int*)alloc((size_t)NN * 4);
    int* cursor = (int*)alloc((size_t)NN * 4);
    int* rowptr = (int*)alloc((size_t)(NN + 1) * 4);
    int* csr_src = (int*)alloc((size_t)NE * 4);
    float* inv_den = (float*)alloc((size_t)NN * 4);
    short* B1hi = (short*)alloc((size_t)3 * 65536 * 2);
    short* B1lo = (short*)alloc((size_t)3 * 65536 * 2);
    short* B2hi = (short*)alloc((size_t)3 * 32768 * 2);
    short* B2lo = (short*)alloc((size_t)3 * 32768 * 2);
    float* bvec = (float*)alloc(512 * 4);
    float* a_hat = (float*)alloc((size_t)NN * CC * 4);
    float* h0 = (float*)alloc((size_t)NN * CC * 4);
    float* h1 = (float*)alloc((size_t)NN * CC * 4);

    hipMemsetAsync(counts, 0, (size_t)NN * 4, stream);
    hipMemsetAsync(cursor, 0, (size_t)NN * 4, stream);

    k_detect<<<1, 64, 0, stream>>>((const int*)edges, flag);
    k_count<<<(NE + 255) / 256, 256, 0, stream>>>(edges, flag, counts);
    k_scan<<<1, 1024, 0, stream>>>(counts, rowptr, inv_den);
    k_bucket<<<(NE + 255) / 256, 256, 0, stream>>>(edges, flag, rowptr, cursor, csr_src);
    int prep_threads = 2 * 3 * C3 * CC + 512;
    k_prep<<<(prep_threads + 255) / 256, 256, 0, stream>>>(weight, w_ih, w_hh, b_ih, b_hh,
                                                           B1hi, B1lo, B2hi, B2lo, bvec);

    const float* hc = x;
    float* bufs[2] = {h0, h1};
    for (int i = 0; i < 3; i++) {
        k_agg<<<25000, 256, 0, stream>>>(hc, rowptr, csr_src, inv_den, a_hat);
        float* hn = bufs[i & 1];
        k_gru_mfma<<<6250, 256, 0, stream>>>(a_hat, hc,
                                             B1hi + (size_t)i * 65536, B1lo + (size_t)i * 65536,
                                             B2hi + (size_t)i * 32768, B2lo + (size_t)i * 32768,
                                             bvec, hn);
        hc = hn;
    }
    k_out<<<25000, 256, 0, stream>>>(hc, out);
}

// Round 3
// 1249.454 us; speedup vs baseline: 1.7575x; 1.5081x over previous
//
#include <hip/hip_runtime.h>
#include <math.h>

#define NN 100000
#define NE 1600000
#define CC 128
#define C3 384

typedef __attribute__((ext_vector_type(4))) float f4;
typedef __attribute__((ext_vector_type(8))) short s8;

__device__ __forceinline__ float sigmoidf_(float x) { return 1.0f / (1.0f + __expf(-x)); }
__device__ __forceinline__ float tanhf_(float x) { return 2.0f / (1.0f + __expf(-2.0f * x)) - 1.0f; }

__device__ __forceinline__ short f2bf(float x) {
    unsigned u = __float_as_uint(x);
    unsigned r = (u + 0x7fffu + ((u >> 16) & 1u)) >> 16;
    return (short)r;
}
__device__ __forceinline__ float bf2f(short s) {
    return __uint_as_float(((unsigned)(unsigned short)s) << 16);
}

// ---- edge dtype detection: int64 => every odd int32 word is a zero high-word ----
__global__ void k_detect(const int* __restrict__ edges, int* __restrict__ flag) {
    if (threadIdx.x == 0) {
        int allz = 1;
        for (int i = 0; i < 32; i++)
            if (edges[2 * i + 1] != 0) allz = 0;
        *flag = allz;  // 1 => int64 layout
    }
}

__device__ __forceinline__ int edge_val(const void* edges, int f, long long idx) {
    return f ? (int)((const long long*)edges)[idx] : ((const int*)edges)[idx];
}

__global__ void k_count(const void* __restrict__ edges, const int* __restrict__ flag,
                        int* __restrict__ counts) {
    int e = blockIdx.x * blockDim.x + threadIdx.x;
    if (e < NE) {
        int f = *flag;
        int d = edge_val(edges, f, (long long)NE + e);
        atomicAdd(&counts[d], 1);
    }
}

__global__ void k_scan(const int* __restrict__ counts, int* __restrict__ rowptr,
                       float* __restrict__ inv_denom) {
    __shared__ int lds[1024];
    int t = threadIdx.x;
    const int CH = 98;
    int lo = t * CH;
    int hi = lo + CH; if (hi > NN) hi = NN;
    int s = 0;
    for (int i = lo; i < hi; i++) s += counts[i];
    lds[t] = s;
    __syncthreads();
    for (int off = 1; off < 1024; off <<= 1) {
        int v = (t >= off) ? lds[t - off] : 0;
        __syncthreads();
        lds[t] += v;
        __syncthreads();
    }
    int base = (t == 0) ? 0 : lds[t - 1];
    for (int i = lo; i < hi; i++) {
        rowptr[i] = base;
        int c = counts[i];
        inv_denom[i] = 1.0f / (float)((c > 1) ? c : 1);
        base += c;
    }
    if (t == 0) rowptr[NN] = NE;
}

__global__ void k_bucket(const void* __restrict__ edges, const int* __restrict__ flag,
                         const int* __restrict__ rowptr, int* __restrict__ cursor,
                         int* __restrict__ csr_src) {
    int e = blockIdx.x * blockDim.x + threadIdx.x;
    if (e < NE) {
        int f = *flag;
        int s = edge_val(edges, f, e);
        int d = edge_val(edges, f, (long long)NE + e);
        int pos = atomicAdd(&cursor[d], 1);
        csr_src[rowptr[d] + pos] = s;
    }
}

// ---- weight prep (unchanged from R2; validated) ----
// B1[i][j][k]: j in [0,256) = r|z rows; k<128 = Wc row j, k>=128 = w_hh[j][k-128].  [256x256]
// B2[i][j][k]: j in [0,128) = Wc n-rows; j in [128,256) = w_hh n-rows.             [256x128]
// bvec[512]: [b_ih[0:256]+b_hh[0:256], b_ih[256:384], b_hh[256:384]]
__global__ void k_prep(const float* __restrict__ weight, const float* __restrict__ w_ih,
                       const float* __restrict__ w_hh, const float* __restrict__ b_ih,
                       const float* __restrict__ b_hh,
                       short* __restrict__ B1hi, short* __restrict__ B1lo,
                       short* __restrict__ B2hi, short* __restrict__ B2lo,
                       float* __restrict__ bvec) {
    const int P1 = 3 * C3 * CC;
    int gid = blockIdx.x * blockDim.x + threadIdx.x;
    if (gid < P1) {
        int i = gid / (C3 * CC);
        int rem = gid % (C3 * CC);
        int j = rem / CC;
        int k = rem % CC;
        const float* Wr = weight + i * CC * CC + k * CC;
        const float* ir = w_ih + j * CC;
        float v = 0.f;
#pragma unroll 4
        for (int c = 0; c < CC; c++) v += Wr[c] * ir[c];
        short hi = f2bf(v);
        short lo = f2bf(v - bf2f(hi));
        if (j < 256) {
            int idx = i * 65536 + j * 256 + k;
            B1hi[idx] = hi; B1lo[idx] = lo;
        } else {
            int idx = i * 32768 + (j - 256) * 128 + k;
            B2hi[idx] = hi; B2lo[idx] = lo;
        }
    } else if (gid < 2 * P1) {
        int g = gid - P1;
        int i = g / (C3 * CC);
        int rem = g % (C3 * CC);
        int j = rem / CC;
        int k = rem % CC;
        float v = w_hh[j * CC + k];
        short hi = f2bf(v);
        short lo = f2bf(v - bf2f(hi));
        if (j < 256) {
            int idx = i * 65536 + j * 256 + 128 + k;
            B1hi[idx] = hi; B1lo[idx] = lo;
        } else {
            int idx = i * 32768 + (j - 256 + 128) * 128 + k;
            B2hi[idx] = hi; B2lo[idx] = lo;
        }
    } else if (gid < 2 * P1 + 512) {
        int j = gid - 2 * P1;
        float v;
        if (j < 256) v = b_ih[j] + b_hh[j];
        else if (j < 384) v = b_ih[j];
        else v = b_hh[j - 128];
        bvec[j] = v;
    }
}

// ---- aggregation: one wave per node, 2-edge unroll for ILP ----
__global__ void k_agg(const float* __restrict__ h, const int* __restrict__ rowptr,
                      const int* __restrict__ csr_src, const float* __restrict__ inv_denom,
                      float* __restrict__ a_hat) {
    int wid = (blockIdx.x * blockDim.x + threadIdx.x) >> 6;
    int lane = threadIdx.x & 63;
    if (wid >= NN) return;
    int lo = rowptr[wid], hi = rowptr[wid + 1];
    float ax = 0.f, ay = 0.f, bx = 0.f, by = 0.f;
    int e = lo;
    for (; e + 1 < hi; e += 2) {
        int s0 = csr_src[e];
        int s1 = csr_src[e + 1];
        float2 v0 = ((const float2*)(h + (long long)s0 * CC))[lane];
        float2 v1 = ((const float2*)(h + (long long)s1 * CC))[lane];
        ax += v0.x; ay += v0.y; bx += v1.x; by += v1.y;
    }
    if (e < hi) {
        int s0 = csr_src[e];
        float2 v0 = ((const float2*)(h + (long long)s0 * CC))[lane];
        ax += v0.x; ay += v0.y;
    }
    float inv = inv_denom[wid];
    float2 r; r.x = (ax + bx) * inv; r.y = (ay + by) * inv;
    ((float2*)(a_hat + (long long)wid * CC))[lane] = r;
}

// ---- fused split-bf16 MFMA GEMM + GRU, v2 ----
// 64 nodes/block, 256 threads (4 waves). Wave w owns gate-feature blocks g = 2w, 2w+1:
// tiles {g (s_r), 8+g (s_z), 16+g (i_n), 24+g (h_n)} x 4 node-chunks -> 24 indep acc chains.
// A (=[a_hat|h] split bf16 hi/lo) stored in LDS in MFMA-fragment order:
//   off_shorts(rr,c) = (c>>2)*2048 + (rr>>4)*512 + (rr&15)*32 + (c&3)*8   (c = 16B chunk = 8 elems)
// so a wave's A-frag read at (ks, chunk) is contiguous per (lm,lq) -> bank-balanced.
// Epilogue is pure register math: for fixed (lane,reg), the 4 tiles hold s_r/s_z/i_n/h_n
// of the SAME (node = chunk*16+lq*4+reg, feature j = g*16+lm).
__global__ __launch_bounds__(256, 2) void k_gru_mfma(
    const float* __restrict__ a_hat, const float* __restrict__ h,
    const short* __restrict__ B1hi, const short* __restrict__ B1lo,
    const short* __restrict__ B2hi, const short* __restrict__ B2lo,
    const float* __restrict__ bvec, float* __restrict__ h_out) {
    __shared__ short Ahi[16384];
    __shared__ short Alo[16384];
    int t = threadIdx.x;
    long long nb = (long long)blockIdx.x * 64;

    // stage + split A: 64 nodes x 256 floats = 2048 chunks of 8; 8 per thread
#pragma unroll
    for (int i = 0; i < 8; i++) {
        int ci = t + 256 * i;
        int rr = ci >> 5;
        int c = ci & 31;
        long long row = nb + rr;
        if (row >= NN) row = NN - 1;
        const float* rp = (c < 16) ? (a_hat + row * CC + c * 8)
                                   : (h + row * CC + (c * 8 - 128));
        float4 v0 = *(const float4*)rp;
        float4 v1 = *(const float4*)(rp + 4);
        float f[8] = {v0.x, v0.y, v0.z, v0.w, v1.x, v1.y, v1.z, v1.w};
        s8 vh, vl;
#pragma unroll
        for (int q = 0; q < 8; q++) {
            short hi = f2bf(f[q]);
            vh[q] = hi;
            vl[q] = f2bf(f[q] - bf2f(hi));
        }
        int off = (c >> 2) * 2048 + (rr >> 4) * 512 + (rr & 15) * 32 + (c & 3) * 8;
        *(s8*)&Ahi[off] = vh;
        *(s8*)&Alo[off] = vl;
    }
    __syncthreads();

    int wv = t >> 6;
    int lane = t & 63;
    int lm = lane & 15;
    int lq = lane >> 4;
    int g0 = 2 * wv;

    f4 aR[2][4], aZ[2][4], aN[2][4], aH[2][4];
#pragma unroll
    for (int gp = 0; gp < 2; gp++) {
        int j = (g0 + gp) * 16 + lm;
        float bR = bvec[j], bZ = bvec[128 + j], bN = bvec[256 + j], bH = bvec[384 + j];
#pragma unroll
        for (int ch = 0; ch < 4; ch++) {
            aR[gp][ch] = (f4){bR, bR, bR, bR};
            aZ[gp][ch] = (f4){bZ, bZ, bZ, bZ};
            aN[gp][ch] = (f4){bN, bN, bN, bN};
            aH[gp][ch] = (f4){bH, bH, bH, bH};
        }
    }

#pragma unroll
    for (int ks = 0; ks < 8; ks++) {
        s8 bRh[2], bRl[2], bZh[2], bZl[2], bGh[2], bGl[2];
#pragma unroll
        for (int gp = 0; gp < 2; gp++) {
            int rowR = (g0 + gp) * 16 + lm;
            int o1 = ks * 32 + lq * 8;
            bRh[gp] = *(const s8*)(B1hi + rowR * 256 + o1);
            bRl[gp] = *(const s8*)(B1lo + rowR * 256 + o1);
            bZh[gp] = *(const s8*)(B1hi + (128 + rowR) * 256 + o1);
            bZl[gp] = *(const s8*)(B1lo + (128 + rowR) * 256 + o1);
            int rowG = (ks < 4) ? rowR : (128 + rowR);
            int o2 = ((ks < 4) ? ks * 32 : (ks - 4) * 32) + lq * 8;
            bGh[gp] = *(const s8*)(B2hi + rowG * 128 + o2);
            bGl[gp] = *(const s8*)(B2lo + rowG * 128 + o2);
        }
#pragma unroll
        for (int ch = 0; ch < 4; ch++) {
            int aoff = ks * 2048 + ch * 512 + lm * 32 + lq * 8;
            s8 ah = *(const s8*)&Ahi[aoff];
            s8 al = *(const s8*)&Alo[aoff];
#pragma unroll
            for (int gp = 0; gp < 2; gp++) {
                aR[gp][ch] = __builtin_amdgcn_mfma_f32_16x16x32_bf16(ah, bRh[gp], aR[gp][ch], 0, 0, 0);
                aR[gp][ch] = __builtin_amdgcn_mfma_f32_16x16x32_bf16(al, bRh[gp], aR[gp][ch], 0, 0, 0);
                aR[gp][ch] = __builtin_amdgcn_mfma_f32_16x16x32_bf16(ah, bRl[gp], aR[gp][ch], 0, 0, 0);
                aZ[gp][ch] = __builtin_amdgcn_mfma_f32_16x16x32_bf16(ah, bZh[gp], aZ[gp][ch], 0, 0, 0);
                aZ[gp][ch] = __builtin_amdgcn_mfma_f32_16x16x32_bf16(al, bZh[gp], aZ[gp][ch], 0, 0, 0);
                aZ[gp][ch] = __builtin_amdgcn_mfma_f32_16x16x32_bf16(ah, bZl[gp], aZ[gp][ch], 0, 0, 0);
                if (ks < 4) {
                    aN[gp][ch] = __builtin_amdgcn_mfma_f32_16x16x32_bf16(ah, bGh[gp], aN[gp][ch], 0, 0, 0);
                    aN[gp][ch] = __builtin_amdgcn_mfma_f32_16x16x32_bf16(al, bGh[gp], aN[gp][ch], 0, 0, 0);
                    aN[gp][ch] = __builtin_amdgcn_mfma_f32_16x16x32_bf16(ah, bGl[gp], aN[gp][ch], 0, 0, 0);
                } else {
                    aH[gp][ch] = __builtin_amdgcn_mfma_f32_16x16x32_bf16(ah, bGh[gp], aH[gp][ch], 0, 0, 0);
                    aH[gp][ch] = __builtin_amdgcn_mfma_f32_16x16x32_bf16(al, bGh[gp], aH[gp][ch], 0, 0, 0);
                    aH[gp][ch] = __builtin_amdgcn_mfma_f32_16x16x32_bf16(ah, bGl[gp], aH[gp][ch], 0, 0, 0);
                }
            }
        }
    }

    // register-only GRU epilogue
#pragma unroll
    for (int gp = 0; gp < 2; gp++) {
        int j = (g0 + gp) * 16 + lm;
        int c = 16 + (j >> 3);
        int obase = (c >> 2) * 2048 + (c & 3) * 8 + (j & 7);
#pragma unroll
        for (int ch = 0; ch < 4; ch++) {
#pragma unroll
            for (int r = 0; r < 4; r++) {
                int node = ch * 16 + lq * 4 + r;
                long long gnode = nb + node;
                int off = obase + ch * 512 + (node & 15) * 32;
                float hp = bf2f(Ahi[off]) + bf2f(Alo[off]);
                float sr = aR[gp][ch][r];
                float sz = aZ[gp][ch][r];
                float in_ = aN[gp][ch][r];
                float hn = aH[gp][ch][r];
                float rg = sigmoidf_(sr);
                float zg = sigmoidf_(sz);
                float nv = tanhf_(in_ + rg * hn);
                if (gnode < NN)
                    h_out[gnode * CC + j] = (1.f - zg) * nv + zg * hp;
            }
        }
    }
}

// ---- out[n] = tanh(mean_c h[n][c]) ----
__global__ void k_out(const float* __restrict__ h, float* __restrict__ out) {
    int wid = (blockIdx.x * blockDim.x + threadIdx.x) >> 6;
    int lane = threadIdx.x & 63;
    if (wid >= NN) return;
    float2 v = ((const float2*)(h + (long long)wid * CC))[lane];
    float s = v.x + v.y;
    for (int off = 32; off; off >>= 1) s += __shfl_down(s, off);
    if (lane == 0) out[wid] = tanhf_(s * (1.0f / 128.0f));
}

extern "C" void kernel_launch(void* const* d_in, const int* in_sizes, int n_in,
                              void* d_out, int out_size, void* d_ws, size_t ws_size,
                              hipStream_t stream) {
    const float* x = (const float*)d_in[0];
    const void* edges = d_in[1];
    const float* weight = (const float*)d_in[2];
    const float* w_ih = (const float*)d_in[3];
    const float* w_hh = (const float*)d_in[4];
    const float* b_ih = (const float*)d_in[5];
    const float* b_hh = (const float*)d_in[6];
    float* out = (float*)d_out;

    char* ws = (char*)d_ws;
    size_t off = 0;
    auto alloc = [&](size_t bytes) -> char* {
        char* p = ws + off;
        off += (bytes + 255) & ~(size_t)255;
        return p;
    };
    int* flag = (int*)alloc(4);
    int* counts = (int*)alloc((size_t)NN * 4);
    int* cursor = (int*)alloc((size_t)NN * 4);
    int* rowptr = (int*)alloc((size_t)(NN + 1) * 4);
    int* csr_src = (int*)alloc((size_t)NE * 4);
    float* inv_den = (float*)alloc((size_t)NN * 4);
    short* B1hi = (short*)alloc((size_t)3 * 65536 * 2);
    short* B1lo = (short*)alloc((size_t)3 * 65536 * 2);
    short* B2hi = (short*)alloc((size_t)3 * 32768 * 2);
    short* B2lo = (short*)alloc((size_t)3 * 32768 * 2);
    float* bvec = (float*)alloc(512 * 4);
    float* a_hat = (float*)alloc((size_t)NN * CC * 4);
    float* h0 = (float*)alloc((size_t)NN * CC * 4);
    float* h1 = (float*)alloc((size_t)NN * CC * 4);

    hipMemsetAsync(counts, 0, (size_t)NN * 4, stream);
    hipMemsetAsync(cursor, 0, (size_t)NN * 4, stream);

    k_detect<<<1, 64, 0, stream>>>((const int*)edges, flag);
    k_count<<<(NE + 255) / 256, 256, 0, stream>>>(edges, flag, counts);
    k_scan<<<1, 1024, 0, stream>>>(counts, rowptr, inv_den);
    k_bucket<<<(NE + 255) / 256, 256, 0, stream>>>(edges, flag, rowptr, cursor, csr_src);
    int prep_threads = 2 * 3 * C3 * CC + 512;
    k_prep<<<(prep_threads + 255) / 256, 256, 0, stream>>>(weight, w_ih, w_hh, b_ih, b_hh,
                                                           B1hi, B1lo, B2hi, B2lo, bvec);

    const float* hc = x;
    float* bufs[2] = {h0, h1};
    const int gru_blocks = (NN + 63) / 64;  // 1563
    for (int i = 0; i < 3; i++) {
        k_agg<<<25000, 256, 0, stream>>>(hc, rowptr, csr_src, inv_den, a_hat);
        float* hn = bufs[i & 1];
        k_gru_mfma<<<gru_blocks, 256, 0, stream>>>(a_hat, hc,
                                                   B1hi + (size_t)i * 65536, B1lo + (size_t)i * 65536,
                                                   B2hi + (size_t)i * 32768, B2lo + (size_t)i * 32768,
                                                   bvec, hn);
        hc = hn;
    }
    k_out<<<25000, 256, 0, stream>>>(hc, out);
}

// Round 4
// 969.366 us; speedup vs baseline: 2.2653x; 1.2889x over previous
//
#include <hip/hip_runtime.h>
#include <math.h>

#define NN 100000
#define NE 1600000
#define CC 128
#define C3 384
#define SCAN_B 256
#define SCAN_NB ((NN + SCAN_B - 1) / SCAN_B)  // 391

typedef __attribute__((ext_vector_type(4))) float f4;
typedef __attribute__((ext_vector_type(8))) short s8;

__device__ __forceinline__ float sigmoidf_(float x) { return 1.0f / (1.0f + __expf(-x)); }
__device__ __forceinline__ float tanhf_(float x) { return 2.0f / (1.0f + __expf(-2.0f * x)) - 1.0f; }

__device__ __forceinline__ short f2bf(float x) {
    unsigned u = __float_as_uint(x);
    unsigned r = (u + 0x7fffu + ((u >> 16) & 1u)) >> 16;
    return (short)r;
}
__device__ __forceinline__ float bf2f(short s) {
    return __uint_as_float(((unsigned)(unsigned short)s) << 16);
}

// ---- edge dtype detection: int64 => every odd int32 word is a zero high-word ----
__global__ void k_detect(const int* __restrict__ edges, int* __restrict__ flag) {
    if (threadIdx.x == 0) {
        int allz = 1;
        for (int i = 0; i < 32; i++)
            if (edges[2 * i + 1] != 0) allz = 0;
        *flag = allz;  // 1 => int64 layout
    }
}

__device__ __forceinline__ int edge_val(const void* edges, int f, long long idx) {
    return f ? (int)((const long long*)edges)[idx] : ((const int*)edges)[idx];
}

__global__ void k_count(const void* __restrict__ edges, const int* __restrict__ flag,
                        int* __restrict__ counts) {
    int e = blockIdx.x * blockDim.x + threadIdx.x;
    if (e < NE) {
        int f = *flag;
        int d = edge_val(edges, f, (long long)NE + e);
        atomicAdd(&counts[d], 1);
    }
}

// ---- multi-block scan: partials -> scan partials -> local scan + emit ----
__global__ void k_scan1(const int* __restrict__ counts, int* __restrict__ bsum) {
    __shared__ int red[4];
    int t = threadIdx.x;
    int i = blockIdx.x * SCAN_B + t;
    int v = (i < NN) ? counts[i] : 0;
#pragma unroll
    for (int off = 32; off; off >>= 1) v += __shfl_down(v, off);
    if ((t & 63) == 0) red[t >> 6] = v;
    __syncthreads();
    if (t == 0) bsum[blockIdx.x] = red[0] + red[1] + red[2] + red[3];
}

__global__ void k_scan2(const int* __restrict__ bsum, int* __restrict__ boff) {
    __shared__ int lds[512];
    int t = threadIdx.x;
    int v = (t < SCAN_NB) ? bsum[t] : 0;
    lds[t] = v;
    __syncthreads();
    for (int off = 1; off < 512; off <<= 1) {
        int u = (t >= off) ? lds[t - off] : 0;
        __syncthreads();
        lds[t] += u;
        __syncthreads();
    }
    if (t < SCAN_NB) boff[t] = lds[t] - v;  // exclusive
}

__global__ void k_scan3(const int* __restrict__ counts, const int* __restrict__ boff,
                        int* __restrict__ rowptr, float* __restrict__ inv_denom) {
    __shared__ int lds[SCAN_B];
    int t = threadIdx.x;
    int i = blockIdx.x * SCAN_B + t;
    int v = (i < NN) ? counts[i] : 0;
    lds[t] = v;
    __syncthreads();
    for (int off = 1; off < SCAN_B; off <<= 1) {
        int u = (t >= off) ? lds[t - off] : 0;
        __syncthreads();
        lds[t] += u;
        __syncthreads();
    }
    if (i < NN) {
        rowptr[i] = boff[blockIdx.x] + lds[t] - v;  // exclusive prefix
        inv_denom[i] = 1.0f / (float)((v > 1) ? v : 1);
    }
    if (i == 0) rowptr[NN] = NE;
}

__global__ void k_bucket(const void* __restrict__ edges, const int* __restrict__ flag,
                         const int* __restrict__ rowptr, int* __restrict__ cursor,
                         int* __restrict__ csr_src) {
    int e = blockIdx.x * blockDim.x + threadIdx.x;
    if (e < NE) {
        int f = *flag;
        int s = edge_val(edges, f, e);
        int d = edge_val(edges, f, (long long)NE + e);
        int pos = atomicAdd(&cursor[d], 1);
        csr_src[rowptr[d] + pos] = s;
    }
}

// ---- weight prep (validated R2) ----
__global__ void k_prep(const float* __restrict__ weight, const float* __restrict__ w_ih,
                       const float* __restrict__ w_hh, const float* __restrict__ b_ih,
                       const float* __restrict__ b_hh,
                       short* __restrict__ B1hi, short* __restrict__ B1lo,
                       short* __restrict__ B2hi, short* __restrict__ B2lo,
                       float* __restrict__ bvec) {
    const int P1 = 3 * C3 * CC;
    int gid = blockIdx.x * blockDim.x + threadIdx.x;
    if (gid < P1) {
        int i = gid / (C3 * CC);
        int rem = gid % (C3 * CC);
        int j = rem / CC;
        int k = rem % CC;
        const float* Wr = weight + i * CC * CC + k * CC;
        const float* ir = w_ih + j * CC;
        float v = 0.f;
#pragma unroll 4
        for (int c = 0; c < CC; c++) v += Wr[c] * ir[c];
        short hi = f2bf(v);
        short lo = f2bf(v - bf2f(hi));
        if (j < 256) {
            int idx = i * 65536 + j * 256 + k;
            B1hi[idx] = hi; B1lo[idx] = lo;
        } else {
            int idx = i * 32768 + (j - 256) * 128 + k;
            B2hi[idx] = hi; B2lo[idx] = lo;
        }
    } else if (gid < 2 * P1) {
        int g = gid - P1;
        int i = g / (C3 * CC);
        int rem = g % (C3 * CC);
        int j = rem / CC;
        int k = rem % CC;
        float v = w_hh[j * CC + k];
        short hi = f2bf(v);
        short lo = f2bf(v - bf2f(hi));
        if (j < 256) {
            int idx = i * 65536 + j * 256 + 128 + k;
            B1hi[idx] = hi; B1lo[idx] = lo;
        } else {
            int idx = i * 32768 + (j - 256 + 128) * 128 + k;
            B2hi[idx] = hi; B2lo[idx] = lo;
        }
    } else if (gid < 2 * P1 + 512) {
        int j = gid - 2 * P1;
        float v;
        if (j < 256) v = b_ih[j] + b_hh[j];
        else if (j < 384) v = b_ih[j];
        else v = b_hh[j - 128];
        bvec[j] = v;
    }
}

// ---- aggregation: one wave per node; half-waves process even/odd edges with float4 ----
// One VMEM instr moves 2 rows (1024 B). Halves combined via shfl at the end.
__global__ void k_agg(const float* __restrict__ h, const int* __restrict__ rowptr,
                      const int* __restrict__ csr_src, const float* __restrict__ inv_denom,
                      float* __restrict__ a_hat) {
    int wid = (blockIdx.x * blockDim.x + threadIdx.x) >> 6;
    int lane = threadIdx.x & 63;
    if (wid >= NN) return;
    int lo = rowptr[wid], hi = rowptr[wid + 1];
    int half = lane >> 5;
    int l32 = lane & 31;
    float ax = 0.f, ay = 0.f, az = 0.f, aw = 0.f;
    for (int e = lo + half; e < hi; e += 2) {
        int s = csr_src[e];
        float4 v = ((const float4*)(h + (long long)s * CC))[l32];
        ax += v.x; ay += v.y; az += v.z; aw += v.w;
    }
    ax += __shfl_down(ax, 32);
    ay += __shfl_down(ay, 32);
    az += __shfl_down(az, 32);
    aw += __shfl_down(aw, 32);
    if (half == 0) {
        float inv = inv_denom[wid];
        float4 r;
        r.x = ax * inv; r.y = ay * inv; r.z = az * inv; r.w = aw * inv;
        ((float4*)(a_hat + (long long)wid * CC))[l32] = r;
    }
}

// ---- fused split-bf16 MFMA GEMM + GRU (validated R3) ----
__global__ __launch_bounds__(256, 2) void k_gru_mfma(
    const float* __restrict__ a_hat, const float* __restrict__ h,
    const short* __restrict__ B1hi, const short* __restrict__ B1lo,
    const short* __restrict__ B2hi, const short* __restrict__ B2lo,
    const float* __restrict__ bvec, float* __restrict__ h_out) {
    __shared__ short Ahi[16384];
    __shared__ short Alo[16384];
    int t = threadIdx.x;
    long long nb = (long long)blockIdx.x * 64;

#pragma unroll
    for (int i = 0; i < 8; i++) {
        int ci = t + 256 * i;
        int rr = ci >> 5;
        int c = ci & 31;
        long long row = nb + rr;
        if (row >= NN) row = NN - 1;
        const float* rp = (c < 16) ? (a_hat + row * CC + c * 8)
                                   : (h + row * CC + (c * 8 - 128));
        float4 v0 = *(const float4*)rp;
        float4 v1 = *(const float4*)(rp + 4);
        float f[8] = {v0.x, v0.y, v0.z, v0.w, v1.x, v1.y, v1.z, v1.w};
        s8 vh, vl;
#pragma unroll
        for (int q = 0; q < 8; q++) {
            short hi = f2bf(f[q]);
            vh[q] = hi;
            vl[q] = f2bf(f[q] - bf2f(hi));
        }
        int off = (c >> 2) * 2048 + (rr >> 4) * 512 + (rr & 15) * 32 + (c & 3) * 8;
        *(s8*)&Ahi[off] = vh;
        *(s8*)&Alo[off] = vl;
    }
    __syncthreads();

    int wv = t >> 6;
    int lane = t & 63;
    int lm = lane & 15;
    int lq = lane >> 4;
    int g0 = 2 * wv;

    f4 aR[2][4], aZ[2][4], aN[2][4], aH[2][4];
#pragma unroll
    for (int gp = 0; gp < 2; gp++) {
        int j = (g0 + gp) * 16 + lm;
        float bR = bvec[j], bZ = bvec[128 + j], bN = bvec[256 + j], bH = bvec[384 + j];
#pragma unroll
        for (int ch = 0; ch < 4; ch++) {
            aR[gp][ch] = (f4){bR, bR, bR, bR};
            aZ[gp][ch] = (f4){bZ, bZ, bZ, bZ};
            aN[gp][ch] = (f4){bN, bN, bN, bN};
            aH[gp][ch] = (f4){bH, bH, bH, bH};
        }
    }

#pragma unroll
    for (int ks = 0; ks < 8; ks++) {
        s8 bRh[2], bRl[2], bZh[2], bZl[2], bGh[2], bGl[2];
#pragma unroll
        for (int gp = 0; gp < 2; gp++) {
            int rowR = (g0 + gp) * 16 + lm;
            int o1 = ks * 32 + lq * 8;
            bRh[gp] = *(const s8*)(B1hi + rowR * 256 + o1);
            bRl[gp] = *(const s8*)(B1lo + rowR * 256 + o1);
            bZh[gp] = *(const s8*)(B1hi + (128 + rowR) * 256 + o1);
            bZl[gp] = *(const s8*)(B1lo + (128 + rowR) * 256 + o1);
            int rowG = (ks < 4) ? rowR : (128 + rowR);
            int o2 = ((ks < 4) ? ks * 32 : (ks - 4) * 32) + lq * 8;
            bGh[gp] = *(const s8*)(B2hi + rowG * 128 + o2);
            bGl[gp] = *(const s8*)(B2lo + rowG * 128 + o2);
        }
#pragma unroll
        for (int ch = 0; ch < 4; ch++) {
            int aoff = ks * 2048 + ch * 512 + lm * 32 + lq * 8;
            s8 ah = *(const s8*)&Ahi[aoff];
            s8 al = *(const s8*)&Alo[aoff];
#pragma unroll
            for (int gp = 0; gp < 2; gp++) {
                aR[gp][ch] = __builtin_amdgcn_mfma_f32_16x16x32_bf16(ah, bRh[gp], aR[gp][ch], 0, 0, 0);
                aR[gp][ch] = __builtin_amdgcn_mfma_f32_16x16x32_bf16(al, bRh[gp], aR[gp][ch], 0, 0, 0);
                aR[gp][ch] = __builtin_amdgcn_mfma_f32_16x16x32_bf16(ah, bRl[gp], aR[gp][ch], 0, 0, 0);
                aZ[gp][ch] = __builtin_amdgcn_mfma_f32_16x16x32_bf16(ah, bZh[gp], aZ[gp][ch], 0, 0, 0);
                aZ[gp][ch] = __builtin_amdgcn_mfma_f32_16x16x32_bf16(al, bZh[gp], aZ[gp][ch], 0, 0, 0);
                aZ[gp][ch] = __builtin_amdgcn_mfma_f32_16x16x32_bf16(ah, bZl[gp], aZ[gp][ch], 0, 0, 0);
                if (ks < 4) {
                    aN[gp][ch] = __builtin_amdgcn_mfma_f32_16x16x32_bf16(ah, bGh[gp], aN[gp][ch], 0, 0, 0);
                    aN[gp][ch] = __builtin_amdgcn_mfma_f32_16x16x32_bf16(al, bGh[gp], aN[gp][ch], 0, 0, 0);
                    aN[gp][ch] = __builtin_amdgcn_mfma_f32_16x16x32_bf16(ah, bGl[gp], aN[gp][ch], 0, 0, 0);
                } else {
                    aH[gp][ch] = __builtin_amdgcn_mfma_f32_16x16x32_bf16(ah, bGh[gp], aH[gp][ch], 0, 0, 0);
                    aH[gp][ch] = __builtin_amdgcn_mfma_f32_16x16x32_bf16(al, bGh[gp], aH[gp][ch], 0, 0, 0);
                    aH[gp][ch] = __builtin_amdgcn_mfma_f32_16x16x32_bf16(ah, bGl[gp], aH[gp][ch], 0, 0, 0);
                }
            }
        }
    }

#pragma unroll
    for (int gp = 0; gp < 2; gp++) {
        int j = (g0 + gp) * 16 + lm;
        int c = 16 + (j >> 3);
        int obase = (c >> 2) * 2048 + (c & 3) * 8 + (j & 7);
#pragma unroll
        for (int ch = 0; ch < 4; ch++) {
#pragma unroll
            for (int r = 0; r < 4; r++) {
                int node = ch * 16 + lq * 4 + r;
                long long gnode = nb + node;
                int off = obase + ch * 512 + (node & 15) * 32;
                float hp = bf2f(Ahi[off]) + bf2f(Alo[off]);
                float sr = aR[gp][ch][r];
                float sz = aZ[gp][ch][r];
                float in_ = aN[gp][ch][r];
                float hn = aH[gp][ch][r];
                float rg = sigmoidf_(sr);
                float zg = sigmoidf_(sz);
                float nv = tanhf_(in_ + rg * hn);
                if (gnode < NN)
                    h_out[gnode * CC + j] = (1.f - zg) * nv + zg * hp;
            }
        }
    }
}

// ---- out[n] = tanh(mean_c h[n][c]) ----
__global__ void k_out(const float* __restrict__ h, float* __restrict__ out) {
    int wid = (blockIdx.x * blockDim.x + threadIdx.x) >> 6;
    int lane = threadIdx.x & 63;
    if (wid >= NN) return;
    float2 v = ((const float2*)(h + (long long)wid * CC))[lane];
    float s = v.x + v.y;
    for (int off = 32; off; off >>= 1) s += __shfl_down(s, off);
    if (lane == 0) out[wid] = tanhf_(s * (1.0f / 128.0f));
}

extern "C" void kernel_launch(void* const* d_in, const int* in_sizes, int n_in,
                              void* d_out, int out_size, void* d_ws, size_t ws_size,
                              hipStream_t stream) {
    const float* x = (const float*)d_in[0];
    const void* edges = d_in[1];
    const float* weight = (const float*)d_in[2];
    const float* w_ih = (const float*)d_in[3];
    const float* w_hh = (const float*)d_in[4];
    const float* b_ih = (const float*)d_in[5];
    const float* b_hh = (const float*)d_in[6];
    float* out = (float*)d_out;

    char* ws = (char*)d_ws;
    size_t off = 0;
    auto alloc = [&](size_t bytes) -> char* {
        char* p = ws + off;
        off += (bytes + 255) & ~(size_t)255;
        return p;
    };
    int* flag = (int*)alloc(4);
    int* counts = (int*)alloc((size_t)NN * 4);
    int* cursor = (int*)alloc((size_t)NN * 4);
    int* rowptr = (int*)alloc((size_t)(NN + 1) * 4);
    int* csr_src = (int*)alloc((size_t)NE * 4);
    float* inv_den = (float*)alloc((size_t)NN * 4);
    int* bsum = (int*)alloc((size_t)SCAN_NB * 4);
    int* boff = (int*)alloc((size_t)SCAN_NB * 4);
    short* B1hi = (short*)alloc((size_t)3 * 65536 * 2);
    short* B1lo = (short*)alloc((size_t)3 * 65536 * 2);
    short* B2hi = (short*)alloc((size_t)3 * 32768 * 2);
    short* B2lo = (short*)alloc((size_t)3 * 32768 * 2);
    float* bvec = (float*)alloc(512 * 4);
    float* a_hat = (float*)alloc((size_t)NN * CC * 4);
    float* h0 = (float*)alloc((size_t)NN * CC * 4);
    float* h1 = (float*)alloc((size_t)NN * CC * 4);

    hipMemsetAsync(counts, 0, (size_t)NN * 4, stream);
    hipMemsetAsync(cursor, 0, (size_t)NN * 4, stream);

    k_detect<<<1, 64, 0, stream>>>((const int*)edges, flag);
    k_count<<<(NE + 255) / 256, 256, 0, stream>>>(edges, flag, counts);
    k_scan1<<<SCAN_NB, SCAN_B, 0, stream>>>(counts, bsum);
    k_scan2<<<1, 512, 0, stream>>>(bsum, boff);
    k_scan3<<<SCAN_NB, SCAN_B, 0, stream>>>(counts, boff, rowptr, inv_den);
    k_bucket<<<(NE + 255) / 256, 256, 0, stream>>>(edges, flag, rowptr, cursor, csr_src);
    int prep_threads = 2 * 3 * C3 * CC + 512;
    k_prep<<<(prep_threads + 255) / 256, 256, 0, stream>>>(weight, w_ih, w_hh, b_ih, b_hh,
                                                           B1hi, B1lo, B2hi, B2lo, bvec);

    const float* hc = x;
    float* bufs[2] = {h0, h1};
    const int gru_blocks = (NN + 63) / 64;  // 1563
    for (int i = 0; i < 3; i++) {
        k_agg<<<25000, 256, 0, stream>>>(hc, rowptr, csr_src, inv_den, a_hat);
        float* hn = bufs[i & 1];
        k_gru_mfma<<<gru_blocks, 256, 0, stream>>>(a_hat, hc,
                                                   B1hi + (size_t)i * 65536, B1lo + (size_t)i * 65536,
                                                   B2hi + (size_t)i * 32768, B2lo + (size_t)i * 32768,
                                                   bvec, hn);
        hc = hn;
    }
    k_out<<<25000, 256, 0, stream>>>(hc, out);
}